// Round 1
// baseline (606.743 us; speedup 1.0000x reference)
//
#include <hip/hip_runtime.h>

// Problem constants (match reference setup_inputs)
#define BB 16
#define TT 32641
#define EE 128
#define LL (TT + EE - 1)            // 32768 groups (power of two)
#define RR 256                      // rows per tile in pass 1
#define TILES ((TT + RR - 1) / RR)  // 128
#define NTHREADS 256

// c(t) = number of (i,j) with i+j==t, 0<=i<TT, 0<=j<EE  (TT >= EE)
__device__ __forceinline__ float groupWeight(int t) {
    int c = min(min(t + 1, EE), LL - t);
    return 1.0f / (float)c;
}

// Pass 1: per tile of RR rows (one batch), accumulate
//   accum[0] += sum over elements of x^2 / c(t)
//   gsum[b*LL + t] += partial anti-diagonal sums
__global__ __launch_bounds__(NTHREADS) void tc_pass1(const float* __restrict__ in,
                                                     float* __restrict__ gsum,
                                                     float* __restrict__ accum) {
    __shared__ float lsum[RR + EE - 1];   // 383 floats
    __shared__ float red[NTHREADS / 64];
    const int tid = threadIdx.x;
    const int r0 = blockIdx.x * RR;
    const int b  = blockIdx.y;
    const int nrows = min(RR, TT - r0);
    const int nvec  = nrows * (EE / 4);

    for (int g = tid; g < RR + EE - 1; g += NTHREADS) lsum[g] = 0.0f;
    __syncthreads();

    const float4* __restrict__ src = (const float4*)(in + ((size_t)b * TT + r0) * EE);
    float s2 = 0.0f;
    // tile is "interior" iff every t in [r0, r0+nrows-1+EE-1] has c == EE,
    // i.e. t >= EE-1 and t <= LL-EE
    const bool interior = (r0 >= EE - 1) && (r0 + nrows - 1 + (EE - 1) <= LL - EE);

    if (interior) {
        for (int v = tid; v < nvec; v += NTHREADS) {
            float4 d = src[v];
            // p = 4v; i_local = p>>7; j = p&127; lidx = i_local + j
            int lidx = (v >> 5) + ((v & 31) << 2);
            s2 += d.x * d.x + d.y * d.y + d.z * d.z + d.w * d.w;
            atomicAdd(&lsum[lidx + 0], d.x);
            atomicAdd(&lsum[lidx + 1], d.y);
            atomicAdd(&lsum[lidx + 2], d.z);
            atomicAdd(&lsum[lidx + 3], d.w);
        }
        s2 *= (1.0f / (float)EE);
    } else {
        for (int v = tid; v < nvec; v += NTHREADS) {
            float4 d = src[v];
            int lidx = (v >> 5) + ((v & 31) << 2);
            int t = r0 + lidx;
            s2 += d.x * d.x * groupWeight(t)
                + d.y * d.y * groupWeight(t + 1)
                + d.z * d.z * groupWeight(t + 2)
                + d.w * d.w * groupWeight(t + 3);
            atomicAdd(&lsum[lidx + 0], d.x);
            atomicAdd(&lsum[lidx + 1], d.y);
            atomicAdd(&lsum[lidx + 2], d.z);
            atomicAdd(&lsum[lidx + 3], d.w);
        }
    }

    // block-reduce s2 -> one global atomic
    for (int o = 32; o > 0; o >>= 1) s2 += __shfl_down(s2, o, 64);
    if ((tid & 63) == 0) red[tid >> 6] = s2;
    __syncthreads();  // also guarantees all lsum atomics are done
    if (tid == 0) {
        atomicAdd(&accum[0], red[0] + red[1] + red[2] + red[3]);
    }

    // flush group partials to global
    const int ng = nrows + EE - 1;
    float* __restrict__ gdst = gsum + (size_t)b * LL + r0;
    for (int g = tid; g < ng; g += NTHREADS) {
        atomicAdd(&gdst[g], lsum[g]);
    }
}

// Pass 2: accum[1] += sum over (b,t) of (gsum * w(t))^2
__global__ __launch_bounds__(NTHREADS) void tc_pass2(const float* __restrict__ gsum,
                                                     float* __restrict__ accum) {
    __shared__ float red[NTHREADS / 64];
    const int N = BB * LL;
    float s1 = 0.0f;
    for (int i = blockIdx.x * NTHREADS + threadIdx.x; i < N; i += gridDim.x * NTHREADS) {
        int t = i & (LL - 1);  // LL is a power of two
        float m = gsum[i] * groupWeight(t);
        s1 += m * m;
    }
    for (int o = 32; o > 0; o >>= 1) s1 += __shfl_down(s1, o, 64);
    if ((threadIdx.x & 63) == 0) red[threadIdx.x >> 6] = s1;
    __syncthreads();
    if (threadIdx.x == 0) atomicAdd(&accum[1], red[0] + red[1] + red[2] + red[3]);
}

__global__ void tc_final(const float* __restrict__ accum, float* __restrict__ out) {
    const float scale = (float)(0.1 / ((double)BB * (double)LL));
    out[0] = (accum[0] - accum[1]) * scale;
}

extern "C" void kernel_launch(void* const* d_in, const int* in_sizes, int n_in,
                              void* d_out, int out_size, void* d_ws, size_t ws_size,
                              hipStream_t stream) {
    const float* in = (const float*)d_in[0];
    float* gsum  = (float*)d_ws;                    // BB*LL floats = 2 MiB
    float* accum = gsum + (size_t)BB * LL;          // [0]=S2, [1]=S1
    float* out   = (float*)d_out;

    // d_ws is poisoned before every launch — zero what we use
    hipMemsetAsync(d_ws, 0, ((size_t)BB * LL + 8) * sizeof(float), stream);

    dim3 g1(TILES, BB);
    tc_pass1<<<g1, NTHREADS, 0, stream>>>(in, gsum, accum);
    tc_pass2<<<1024, NTHREADS, 0, stream>>>(gsum, accum);
    tc_final<<<1, 1, 0, stream>>>(accum, out);
}

// Round 2
// 366.058 us; speedup vs baseline: 1.6575x; 1.6575x over previous
//
#include <hip/hip_runtime.h>

// Problem constants (match reference setup_inputs)
#define BB 16
#define TT 32641
#define EE 128
#define LL (TT + EE - 1)             // 32768 = 2^15 groups
#define RT 64                        // rows per tile in pass 1
#define NT ((TT + RT - 1) / RT)      // 511 tiles per batch
#define GPT (RT + EE - 1)            // 191 group partials per tile
#define SLOT 192                     // stride: 191 partials + 1 s2 slot
#define NTH 256
#define P2_BLOCKS 256

// c(t) = |{(i,j): i+j==t, 0<=i<TT, 0<=j<EE}|  (TT >= EE)
__device__ __forceinline__ float groupWeight(int t) {
    int c = min(min(t + 1, EE), LL - t);
    return 1.0f / (float)c;
}

// Pass 1: one block per (tile, batch).
//  Phase A: stage RT x EE tile in LDS (plain writes), accumulate s2 = sum x^2*w(t).
//  Phase B: thread d (< GPT) sums anti-diagonal d from LDS (stride-1, conflict-free),
//           writes partial group sum non-atomically. Thread 0 writes block s2 partial.
__global__ __launch_bounds__(NTH) void tc_pass1(const float* __restrict__ in,
                                                float* __restrict__ part) {
    __shared__ float lsum[RT * EE];        // 32 KB
    __shared__ float red[NTH / 64];
    const int tid = threadIdx.x;
    const int k   = blockIdx.x;            // tile index
    const int b   = blockIdx.y;
    const int r0  = k * RT;
    const int nrows = min(RT, TT - r0);

    const float4* __restrict__ src = (const float4*)(in + ((size_t)b * TT + r0) * EE);
    float4* __restrict__ ldst = (float4*)lsum;

    float s2 = 0.0f;
    // interior iff every covered group t in [r0, r0+nrows-1+127] has c(t)==EE
    const bool interior = (r0 >= EE - 1) && (r0 + nrows - 1 + (EE - 1) <= LL - EE);

    if (interior) {
        // interior tiles always have nrows == RT
        #pragma unroll
        for (int u = 0; u < RT * (EE / 4) / NTH; ++u) {
            int v = tid + u * NTH;
            float4 d = src[v];
            s2 += d.x * d.x + d.y * d.y + d.z * d.z + d.w * d.w;
            ldst[v] = d;
        }
        s2 *= (1.0f / (float)EE);
    } else {
        const int nvec = nrows * (EE / 4);
        for (int v = tid; v < nvec; v += NTH) {
            float4 d = src[v];
            int t = r0 + (v >> 5) + ((v & 31) << 2);   // row = v>>5, col = 4*(v&31)
            s2 += d.x * d.x * groupWeight(t)
                + d.y * d.y * groupWeight(t + 1)
                + d.z * d.z * groupWeight(t + 2)
                + d.w * d.w * groupWeight(t + 3);
            ldst[v] = d;
        }
    }
    __syncthreads();

    float* __restrict__ base = part + ((size_t)b * NT + k) * SLOT;

    // Phase B: anti-diagonal partial sums. Lane g reads lsum[i*EE + (g-i)]:
    // consecutive lanes -> consecutive LDS addresses -> conflict-free.
    if (tid < GPT) {
        const int d = tid;
        float g = 0.0f;
        const int ilo = max(0, d - (EE - 1));
        const int ihi = min(nrows - 1, d);
        for (int i = ilo; i <= ihi; ++i) g += lsum[i * EE + (d - i)];
        base[d] = g;   // zero when loop empty (groups beyond nrows+126 in last tile)
    }

    // block-reduce s2 -> one non-atomic slot write
    for (int o = 32; o > 0; o >>= 1) s2 += __shfl_down(s2, o, 64);
    if ((tid & 63) == 0) red[tid >> 6] = s2;
    __syncthreads();
    if (tid == 0) base[GPT] = red[0] + red[1] + red[2] + red[3];
}

// Pass 2: S1 = sum over (b,t) of (g(b,t)*w(t))^2 from <=3 tile partials each;
//         S2 = sum of per-tile s2 slots. Block partials written non-atomically.
__global__ __launch_bounds__(NTH) void tc_pass2(const float* __restrict__ part,
                                                float* __restrict__ part2) {
    __shared__ float redA[NTH / 64], redB[NTH / 64];
    float s1 = 0.0f, s2 = 0.0f;
    const int N = BB * LL;
    for (int idx = blockIdx.x * NTH + threadIdx.x; idx < N; idx += gridDim.x * NTH) {
        const int t  = idx & (LL - 1);
        const int b  = idx >> 15;              // LL = 2^15
        const int k0 = t >> 6;                 // RT = 64
        float g = 0.0f;
        #pragma unroll
        for (int dk = 2; dk >= 0; --dk) {
            const int k = k0 - dk;
            const int d = t - (k << 6);
            if (k >= 0 && k < NT && d >= 0 && d < GPT)
                g += part[((size_t)b * NT + k) * SLOT + d];
        }
        const float m = g * groupWeight(t);
        s1 += m * m;
    }
    const int NS = BB * NT;
    for (int idx = blockIdx.x * NTH + threadIdx.x; idx < NS; idx += gridDim.x * NTH) {
        s2 += part[(size_t)idx * SLOT + GPT];
    }
    for (int o = 32; o > 0; o >>= 1) {
        s1 += __shfl_down(s1, o, 64);
        s2 += __shfl_down(s2, o, 64);
    }
    if ((threadIdx.x & 63) == 0) { redA[threadIdx.x >> 6] = s1; redB[threadIdx.x >> 6] = s2; }
    __syncthreads();
    if (threadIdx.x == 0) {
        part2[blockIdx.x * 2 + 0] = redA[0] + redA[1] + redA[2] + redA[3];
        part2[blockIdx.x * 2 + 1] = redB[0] + redB[1] + redB[2] + redB[3];
    }
}

__global__ __launch_bounds__(NTH) void tc_final(const float* __restrict__ part2,
                                                float* __restrict__ out) {
    __shared__ float redA[NTH / 64], redB[NTH / 64];
    float s1 = 0.0f, s2 = 0.0f;
    for (int i = threadIdx.x; i < P2_BLOCKS; i += NTH) {
        s1 += part2[i * 2 + 0];
        s2 += part2[i * 2 + 1];
    }
    for (int o = 32; o > 0; o >>= 1) {
        s1 += __shfl_down(s1, o, 64);
        s2 += __shfl_down(s2, o, 64);
    }
    if ((threadIdx.x & 63) == 0) { redA[threadIdx.x >> 6] = s1; redB[threadIdx.x >> 6] = s2; }
    __syncthreads();
    if (threadIdx.x == 0) {
        const float scale = (float)(0.1 / ((double)BB * (double)LL));
        out[0] = (redB[0] + redB[1] + redB[2] + redB[3]
                - (redA[0] + redA[1] + redA[2] + redA[3])) * scale;
    }
}

extern "C" void kernel_launch(void* const* d_in, const int* in_sizes, int n_in,
                              void* d_out, int out_size, void* d_ws, size_t ws_size,
                              hipStream_t stream) {
    const float* in = (const float*)d_in[0];
    float* part  = (float*)d_ws;                          // BB*NT*SLOT floats ~ 6.3 MB
    float* part2 = part + (size_t)BB * NT * SLOT;         // P2_BLOCKS*2 floats
    float* out   = (float*)d_out;

    dim3 g1(NT, BB);
    tc_pass1<<<g1, NTH, 0, stream>>>(in, part);
    tc_pass2<<<P2_BLOCKS, NTH, 0, stream>>>(part, part2);
    tc_final<<<1, NTH, 0, stream>>>(part2, out);
}